// Round 4
// baseline (207.731 us; speedup 1.0000x reference)
//
#include <hip/hip_runtime.h>
#include <cstdint>
#include <cstddef>

// Problem dims
#define BB 8
#define HH 512
#define PP 512
#define LL 2048

typedef __attribute__((ext_vector_type(8))) __bf16 bf16x8;
typedef __attribute__((ext_vector_type(4))) float f32x4;

__device__ __forceinline__ uint16_t f2bf(float f) {
  uint32_t u = __builtin_bit_cast(uint32_t, f);
  u += 0x7FFFu + ((u >> 16) & 1u);   // RNE
  return (uint16_t)(u >> 16);
}

// ---------------------------------------------------------------------------
// prep: A1 (1024x512 bf16) = [B_re; B_im], A2 (512x1024 bf16) = [C_re, -C_im],
//       Dd (512 f32) = diag(D)
// ---------------------------------------------------------------------------
__global__ __launch_bounds__(256) void prep_mats(
    const float* __restrict__ Bbar, const float* __restrict__ Cri,
    const float* __restrict__ Dm,
    uint16_t* __restrict__ A1, uint16_t* __restrict__ A2,
    float* __restrict__ Dd) {
  int idx = blockIdx.x * 256 + threadIdx.x;   // 0 .. 512*512-1
  int p = idx >> 9, h = idx & 511;
  A1[(size_t)p * 512 + h]          = f2bf(Bbar[((size_t)p * 512 + h) * 2 + 0]);
  A1[(size_t)(512 + p) * 512 + h]  = f2bf(Bbar[((size_t)p * 512 + h) * 2 + 1]);
  int h2 = idx >> 9, p2 = idx & 511;
  A2[(size_t)h2 * 1024 + p2]        = f2bf( Cri[((size_t)h2 * 512 + p2) * 2 + 0]);
  A2[(size_t)h2 * 1024 + 512 + p2]  = f2bf(-Cri[((size_t)h2 * 512 + p2) * 2 + 1]);
  if (idx < 512) Dd[idx] = Dm[(size_t)idx * 512 + idx];
}

// ---------------------------------------------------------------------------
// scan: in-place on Bu (B, 1024, 2048) bf16 (rows p = re, rows 512+p = im)
// ---------------------------------------------------------------------------
__global__ __launch_bounds__(256) void scan_kernel(
    const float* __restrict__ Lam, uint16_t* __restrict__ Bu) {
  const int gt = blockIdx.x * 256 + threadIdx.x;
  const int wave = gt >> 6, lane = gt & 63;
  const int b = wave >> 9, p = wave & 511;
  const float lr = Lam[p * 2 + 0], li = Lam[p * 2 + 1];
  float ar = lr, ai = li;
#pragma unroll
  for (int s = 0; s < 5; ++s) { float nr = ar * ar - ai * ai, ni = 2.f * ar * ai; ar = nr; ai = ni; }

  uint16_t* rowre = Bu + ((size_t)(b * 1024 + p)) * 2048 + lane * 32;
  uint16_t* rowim = Bu + ((size_t)(b * 1024 + 512 + p)) * 2048 + lane * 32;
  uint4 vr[4], vi[4];
#pragma unroll
  for (int q = 0; q < 4; ++q) { vr[q] = ((const uint4*)rowre)[q]; vi[q] = ((const uint4*)rowim)[q]; }

  float xr[32], xi[32];
  float sr = 0.f, si = 0.f;
#pragma unroll
  for (int q = 0; q < 4; ++q) {
    uint32_t wr[4] = {vr[q].x, vr[q].y, vr[q].z, vr[q].w};
    uint32_t wi[4] = {vi[q].x, vi[q].y, vi[q].z, vi[q].w};
#pragma unroll
    for (int d = 0; d < 4; ++d) {
      float br0 = __builtin_bit_cast(float, wr[d] << 16);
      float bi0 = __builtin_bit_cast(float, wi[d] << 16);
      float br1 = __builtin_bit_cast(float, wr[d] & 0xFFFF0000u);
      float bi1 = __builtin_bit_cast(float, wi[d] & 0xFFFF0000u);
      int j = q * 8 + d * 2;
      float nr = lr * sr - li * si + br0, ni = lr * si + li * sr + bi0;
      sr = nr; si = ni; xr[j] = sr; xi[j] = si;
      nr = lr * sr - li * si + br1; ni = lr * si + li * sr + bi1;
      sr = nr; si = ni; xr[j + 1] = sr; xi[j + 1] = si;
    }
  }
  float Ar = ar, Ai = ai, Sr = sr, Si = si;
#pragma unroll
  for (int off = 1; off < 64; off <<= 1) {
    float pAr = __shfl_up(Ar, off), pAi = __shfl_up(Ai, off);
    float pSr = __shfl_up(Sr, off), pSi = __shfl_up(Si, off);
    if (lane >= off) {
      float tSr = Ar * pSr - Ai * pSi + Sr;
      float tSi = Ar * pSi + Ai * pSr + Si;
      float tAr = Ar * pAr - Ai * pAi;
      float tAi = Ar * pAi + Ai * pAr;
      Sr = tSr; Si = tSi; Ar = tAr; Ai = tAi;
    }
  }
  float Cr = __shfl_up(Sr, 1), Ci = __shfl_up(Si, 1);
  if (lane == 0) { Cr = 0.f; Ci = 0.f; }
  float fr_ = lr * Cr - li * Ci, fi_ = lr * Ci + li * Cr;
#pragma unroll
  for (int j = 0; j < 32; ++j) {
    xr[j] += fr_; xi[j] += fi_;
    float nfr = fr_ * lr - fi_ * li, nfi = fr_ * li + fi_ * lr;
    fr_ = nfr; fi_ = nfi;
  }
#pragma unroll
  for (int q = 0; q < 4; ++q) {
    uint32_t wr[4], wi[4];
#pragma unroll
    for (int d = 0; d < 4; ++d) {
      int j = q * 8 + d * 2;
      wr[d] = (uint32_t)f2bf(xr[j]) | ((uint32_t)f2bf(xr[j + 1]) << 16);
      wi[d] = (uint32_t)f2bf(xi[j]) | ((uint32_t)f2bf(xi[j + 1]) << 16);
    }
    ((uint4*)rowre)[q] = make_uint4(wr[0], wr[1], wr[2], wr[3]);
    ((uint4*)rowim)[q] = make_uint4(wi[0], wi[1], wi[2], wi[3]);
  }
}

// ---------------------------------------------------------------------------
// GEMM1: Bu[b,m,l] = sum_h A1[m,h]*u[b,h,l]. M=1024, N=2048, K=512.
// K-loop: BK=64 pairs, dbuf B-LDS only (A frags direct from global, L2-hot,
// double-buffered one pair ahead). One barrier per 64-k.
// ---------------------------------------------------------------------------
__global__ __launch_bounds__(256) void gemm1_fused(
    const uint16_t* __restrict__ A, const float* __restrict__ U,
    uint16_t* __restrict__ Bu) {
  __shared__ __align__(16) uint16_t Blds[2][2][128 * 40];
  const int t = threadIdx.x, lane = t & 63, w = t >> 6;
  const int m0 = blockIdx.y * 128, n0 = blockIdx.x * 128, b = blockIdx.z;

  const int kp = t >> 4, lg = t & 15;                       // k-pair, l-group
  const float* gB = U + ((size_t)b * 512 + 2 * kp) * 2048 + n0 + lg * 8;
  const int bcol = ((kp >> 2) ^ (lg & 3)) * 8 + (kp & 3) * 2;

  const int wm = (w >> 1) * 64, wn = (w & 1) * 64;
  const int fr = lane & 15, fq = lane >> 4;
  const uint16_t* gA = A + (size_t)(m0 + wm + fr) * 512 + fq * 8;

  f32x4 acc[4][4];
#pragma unroll
  for (int i = 0; i < 4; ++i)
#pragma unroll
    for (int j = 0; j < 4; ++j) acc[i][j] = (f32x4){0.f, 0.f, 0.f, 0.f};

  bf16x8 afA[2][4], afB[2][4];
  float4 p0[2], p1[2], p2[2], p3[2];   // [sub]: rows 2kp (p0,p1) / 2kp+1 (p2,p3)

  // ---- prologue: pair 0
#pragma unroll
  for (int s = 0; s < 2; ++s) {
    const float* sp = gB + (size_t)(32 * s) * 2048;
    p0[s] = *(const float4*)(sp);
    p1[s] = *(const float4*)(sp + 4);
    p2[s] = *(const float4*)(sp + 2048);
    p3[s] = *(const float4*)(sp + 2052);
  }
#pragma unroll
  for (int i = 0; i < 4; ++i) {
    afA[0][i] = *(const bf16x8*)(gA + (size_t)i * 16 * 512);
    afB[0][i] = *(const bf16x8*)(gA + (size_t)i * 16 * 512 + 32);
  }
#pragma unroll
  for (int s = 0; s < 2; ++s) {
    float r0[8] = {p0[s].x, p0[s].y, p0[s].z, p0[s].w, p1[s].x, p1[s].y, p1[s].z, p1[s].w};
    float r1[8] = {p2[s].x, p2[s].y, p2[s].z, p2[s].w, p3[s].x, p3[s].y, p3[s].z, p3[s].w};
#pragma unroll
    for (int j = 0; j < 8; ++j)
      *(uint32_t*)&Blds[0][s][(lg * 8 + j) * 40 + bcol] =
          (uint32_t)f2bf(r0[j]) | ((uint32_t)f2bf(r1[j]) << 16);
  }
  __syncthreads();

#pragma unroll 2
  for (int it = 0; it < 8; ++it) {               // 8 pairs x 64k = 512
    const int cur = it & 1, nxt = cur ^ 1;
    const bool pre = (it < 7);
    const int kn = (it + 1) * 64;
    if (pre) {
      // prefetch next pair: B globals + A fragments (consumed next iter)
#pragma unroll
      for (int s = 0; s < 2; ++s) {
        const float* sp = gB + (size_t)(kn + 32 * s) * 2048;
        p0[s] = *(const float4*)(sp);
        p1[s] = *(const float4*)(sp + 4);
        p2[s] = *(const float4*)(sp + 2048);
        p3[s] = *(const float4*)(sp + 2052);
      }
#pragma unroll
      for (int i = 0; i < 4; ++i) {
        afA[nxt][i] = *(const bf16x8*)(gA + (size_t)i * 16 * 512 + kn);
        afB[nxt][i] = *(const bf16x8*)(gA + (size_t)i * 16 * 512 + kn + 32);
      }
    }
    // sub0 MFMA
    bf16x8 bfr[4];
#pragma unroll
    for (int j = 0; j < 4; ++j) {
      int n = wn + j * 16 + fr;
      bfr[j] = *(const bf16x8*)&Blds[cur][0][n * 40 + ((fq ^ ((n >> 3) & 3)) * 8)];
    }
#pragma unroll
    for (int i = 0; i < 4; ++i)
#pragma unroll
      for (int j = 0; j < 4; ++j)
        acc[i][j] = __builtin_amdgcn_mfma_f32_16x16x32_bf16(afA[cur][i], bfr[j], acc[i][j], 0, 0, 0);
    if (pre) {  // pack sub0 of next pair (vmcnt window = sub0 MFMA phase)
      float r0[8] = {p0[0].x, p0[0].y, p0[0].z, p0[0].w, p1[0].x, p1[0].y, p1[0].z, p1[0].w};
      float r1[8] = {p2[0].x, p2[0].y, p2[0].z, p2[0].w, p3[0].x, p3[0].y, p3[0].z, p3[0].w};
#pragma unroll
      for (int j = 0; j < 8; ++j)
        *(uint32_t*)&Blds[nxt][0][(lg * 8 + j) * 40 + bcol] =
            (uint32_t)f2bf(r0[j]) | ((uint32_t)f2bf(r1[j]) << 16);
    }
    // sub1 MFMA
#pragma unroll
    for (int j = 0; j < 4; ++j) {
      int n = wn + j * 16 + fr;
      bfr[j] = *(const bf16x8*)&Blds[cur][1][n * 40 + ((fq ^ ((n >> 3) & 3)) * 8)];
    }
#pragma unroll
    for (int i = 0; i < 4; ++i)
#pragma unroll
      for (int j = 0; j < 4; ++j)
        acc[i][j] = __builtin_amdgcn_mfma_f32_16x16x32_bf16(afB[cur][i], bfr[j], acc[i][j], 0, 0, 0);
    if (pre) {
      float r0[8] = {p0[1].x, p0[1].y, p0[1].z, p0[1].w, p1[1].x, p1[1].y, p1[1].z, p1[1].w};
      float r1[8] = {p2[1].x, p2[1].y, p2[1].z, p2[1].w, p3[1].x, p3[1].y, p3[1].z, p3[1].w};
#pragma unroll
      for (int j = 0; j < 8; ++j)
        *(uint32_t*)&Blds[nxt][1][(lg * 8 + j) * 40 + bcol] =
            (uint32_t)f2bf(r0[j]) | ((uint32_t)f2bf(r1[j]) << 16);
      __syncthreads();
    }
  }

  uint16_t* O = Bu + ((size_t)b * 1024 + m0) * 2048 + n0;
#pragma unroll
  for (int i = 0; i < 4; ++i)
#pragma unroll
    for (int j = 0; j < 4; ++j)
#pragma unroll
      for (int r = 0; r < 4; ++r) {
        int mm = wm + i * 16 + fq * 4 + r;
        int nn = wn + j * 16 + fr;
        O[(size_t)mm * 2048 + nn] = f2bf(acc[i][j][r]);
      }
}

// ---------------------------------------------------------------------------
// GEMM2: out[b,h,l] = gelu(sum_k A2[h,k]*x[b,k,l] + Dd[h]*u[b,h,l])
// M=512, N=2048, K=1024; same pair-pipelined structure, bf16 B source.
// ---------------------------------------------------------------------------
__global__ __launch_bounds__(256) void gemm2_fused(
    const uint16_t* __restrict__ A, const uint16_t* __restrict__ X,
    float* __restrict__ Out, const float* __restrict__ Dd,
    const float* __restrict__ Uu) {
  __shared__ __align__(16) uint16_t Blds[2][2][128 * 40];
  const int t = threadIdx.x, lane = t & 63, w = t >> 6;
  const int m0 = blockIdx.y * 128, n0 = blockIdx.x * 128, b = blockIdx.z;

  const int kp = t >> 4, lg = t & 15;
  const uint16_t* gB = X + ((size_t)b * 1024 + 2 * kp) * 2048 + n0 + lg * 8;
  const int bcol = ((kp >> 2) ^ (lg & 3)) * 8 + (kp & 3) * 2;

  const int wm = (w >> 1) * 64, wn = (w & 1) * 64;
  const int fr = lane & 15, fq = lane >> 4;
  const uint16_t* gA = A + (size_t)(m0 + wm + fr) * 1024 + fq * 8;

  f32x4 acc[4][4];
#pragma unroll
  for (int i = 0; i < 4; ++i)
#pragma unroll
    for (int j = 0; j < 4; ++j) acc[i][j] = (f32x4){0.f, 0.f, 0.f, 0.f};

  bf16x8 afA[2][4], afB[2][4];
  uint4 q0[2], q1[2];   // [sub]: row 2kp / 2kp+1

  // ---- prologue: pair 0
#pragma unroll
  for (int s = 0; s < 2; ++s) {
    const uint16_t* sp = gB + (size_t)(32 * s) * 2048;
    q0[s] = *(const uint4*)(sp);
    q1[s] = *(const uint4*)(sp + 2048);
  }
#pragma unroll
  for (int i = 0; i < 4; ++i) {
    afA[0][i] = *(const bf16x8*)(gA + (size_t)i * 16 * 1024);
    afB[0][i] = *(const bf16x8*)(gA + (size_t)i * 16 * 1024 + 32);
  }
#pragma unroll
  for (int s = 0; s < 2; ++s) {
    uint32_t u0[4] = {q0[s].x, q0[s].y, q0[s].z, q0[s].w};
    uint32_t u1[4] = {q1[s].x, q1[s].y, q1[s].z, q1[s].w};
#pragma unroll
    for (int d = 0; d < 4; ++d) {
      *(uint32_t*)&Blds[0][s][(lg * 8 + 2 * d + 0) * 40 + bcol] = (u0[d] & 0xFFFFu) | (u1[d] << 16);
      *(uint32_t*)&Blds[0][s][(lg * 8 + 2 * d + 1) * 40 + bcol] = (u0[d] >> 16) | (u1[d] & 0xFFFF0000u);
    }
  }
  __syncthreads();

#pragma unroll 2
  for (int it = 0; it < 16; ++it) {              // 16 pairs x 64k = 1024
    const int cur = it & 1, nxt = cur ^ 1;
    const bool pre = (it < 15);
    const int kn = (it + 1) * 64;
    if (pre) {
#pragma unroll
      for (int s = 0; s < 2; ++s) {
        const uint16_t* sp = gB + (size_t)(kn + 32 * s) * 2048;
        q0[s] = *(const uint4*)(sp);
        q1[s] = *(const uint4*)(sp + 2048);
      }
#pragma unroll
      for (int i = 0; i < 4; ++i) {
        afA[nxt][i] = *(const bf16x8*)(gA + (size_t)i * 16 * 1024 + kn);
        afB[nxt][i] = *(const bf16x8*)(gA + (size_t)i * 16 * 1024 + kn + 32);
      }
    }
    // sub0
    bf16x8 bfr[4];
#pragma unroll
    for (int j = 0; j < 4; ++j) {
      int n = wn + j * 16 + fr;
      bfr[j] = *(const bf16x8*)&Blds[cur][0][n * 40 + ((fq ^ ((n >> 3) & 3)) * 8)];
    }
#pragma unroll
    for (int i = 0; i < 4; ++i)
#pragma unroll
      for (int j = 0; j < 4; ++j)
        acc[i][j] = __builtin_amdgcn_mfma_f32_16x16x32_bf16(afA[cur][i], bfr[j], acc[i][j], 0, 0, 0);
    if (pre) {
      uint32_t u0[4] = {q0[0].x, q0[0].y, q0[0].z, q0[0].w};
      uint32_t u1[4] = {q1[0].x, q1[0].y, q1[0].z, q1[0].w};
#pragma unroll
      for (int d = 0; d < 4; ++d) {
        *(uint32_t*)&Blds[nxt][0][(lg * 8 + 2 * d + 0) * 40 + bcol] = (u0[d] & 0xFFFFu) | (u1[d] << 16);
        *(uint32_t*)&Blds[nxt][0][(lg * 8 + 2 * d + 1) * 40 + bcol] = (u0[d] >> 16) | (u1[d] & 0xFFFF0000u);
      }
    }
    // sub1
#pragma unroll
    for (int j = 0; j < 4; ++j) {
      int n = wn + j * 16 + fr;
      bfr[j] = *(const bf16x8*)&Blds[cur][1][n * 40 + ((fq ^ ((n >> 3) & 3)) * 8)];
    }
#pragma unroll
    for (int i = 0; i < 4; ++i)
#pragma unroll
      for (int j = 0; j < 4; ++j)
        acc[i][j] = __builtin_amdgcn_mfma_f32_16x16x32_bf16(afB[cur][i], bfr[j], acc[i][j], 0, 0, 0);
    if (pre) {
      uint32_t u0[4] = {q0[1].x, q0[1].y, q0[1].z, q0[1].w};
      uint32_t u1[4] = {q1[1].x, q1[1].y, q1[1].z, q1[1].w};
#pragma unroll
      for (int d = 0; d < 4; ++d) {
        *(uint32_t*)&Blds[nxt][1][(lg * 8 + 2 * d + 0) * 40 + bcol] = (u0[d] & 0xFFFFu) | (u1[d] << 16);
        *(uint32_t*)&Blds[nxt][1][(lg * 8 + 2 * d + 1) * 40 + bcol] = (u0[d] >> 16) | (u1[d] & 0xFFFF0000u);
      }
      __syncthreads();
    }
  }

  const size_t base = ((size_t)b * 512 + m0) * 2048 + n0;
  float* O = Out + base;
  const float* Ub = Uu + base;
#pragma unroll
  for (int i = 0; i < 4; ++i)
#pragma unroll
    for (int r = 0; r < 4; ++r) {
      int mm = wm + i * 16 + fq * 4 + r;
      float dv = Dd[m0 + mm];
#pragma unroll
      for (int j = 0; j < 4; ++j) {
        int nn = wn + j * 16 + fr;
        float xv = acc[i][j][r] + dv * Ub[(size_t)mm * 2048 + nn];
        O[(size_t)mm * 2048 + nn] = 0.5f * xv * (1.f + erff(xv * 0.70710678118654752f));
      }
    }
}

// ---------------------------------------------------------------------------
extern "C" void kernel_launch(void* const* d_in, const int* in_sizes, int n_in,
                              void* d_out, int out_size, void* d_ws, size_t ws_size,
                              hipStream_t stream) {
  const float* u    = (const float*)d_in[0];   // (8,512,2048)
  const float* Lam  = (const float*)d_in[1];   // (512,2)
  const float* Bbar = (const float*)d_in[2];   // (512,512,2)
  const float* Cri  = (const float*)d_in[3];   // (512,512,2)
  const float* Dm   = (const float*)d_in[4];   // (512,512)
  float* out = (float*)d_out;

  char* ws = (char*)d_ws;
  uint16_t* Bu = (uint16_t*)(ws);                    // (8,1024,2048) bf16, 33.55 MB
  uint16_t* A1 = (uint16_t*)(ws + 33554432);         // (1024,512) bf16, 1 MB
  uint16_t* A2 = (uint16_t*)(ws + 34603008);         // (512,1024) bf16, 1 MB
  float*    Dd = (float*)   (ws + 35651584);         // (512) f32

  prep_mats<<<1024, 256, 0, stream>>>(Bbar, Cri, Dm, A1, A2, Dd);
  gemm1_fused<<<dim3(16, 8, BB), 256, 0, stream>>>(A1, u, Bu);
  scan_kernel<<<1024, 256, 0, stream>>>(Lam, Bu);
  gemm2_fused<<<dim3(16, 4, BB), 256, 0, stream>>>(A2, Bu, out, Dd, u);
}

// Round 5
// 205.331 us; speedup vs baseline: 1.0117x; 1.0117x over previous
//
#include <hip/hip_runtime.h>
#include <cstdint>
#include <cstddef>

// Problem dims
#define BB 8
#define HH 512
#define PP 512
#define LL 2048

typedef __attribute__((ext_vector_type(8))) __bf16 bf16x8;
typedef __attribute__((ext_vector_type(4))) float f32x4;

__device__ __forceinline__ uint16_t f2bf(float f) {
  uint32_t u = __builtin_bit_cast(uint32_t, f);
  u += 0x7FFFu + ((u >> 16) & 1u);   // RNE
  return (uint16_t)(u >> 16);
}

// ---------------------------------------------------------------------------
// prep: A1 (1024x512 bf16) = [B_re; B_im], A2 (512x1024 bf16) = [C_re, -C_im],
//       Dd (512 f32) = diag(D)
// ---------------------------------------------------------------------------
__global__ __launch_bounds__(256) void prep_mats(
    const float* __restrict__ Bbar, const float* __restrict__ Cri,
    const float* __restrict__ Dm,
    uint16_t* __restrict__ A1, uint16_t* __restrict__ A2,
    float* __restrict__ Dd) {
  int idx = blockIdx.x * 256 + threadIdx.x;   // 0 .. 512*512-1
  int p = idx >> 9, h = idx & 511;
  A1[(size_t)p * 512 + h]          = f2bf(Bbar[((size_t)p * 512 + h) * 2 + 0]);
  A1[(size_t)(512 + p) * 512 + h]  = f2bf(Bbar[((size_t)p * 512 + h) * 2 + 1]);
  int h2 = idx >> 9, p2 = idx & 511;
  A2[(size_t)h2 * 1024 + p2]        = f2bf( Cri[((size_t)h2 * 512 + p2) * 2 + 0]);
  A2[(size_t)h2 * 1024 + 512 + p2]  = f2bf(-Cri[((size_t)h2 * 512 + p2) * 2 + 1]);
  if (idx < 512) Dd[idx] = Dm[(size_t)idx * 512 + idx];
}

// ---------------------------------------------------------------------------
// scan: in-place on Bu (B, 1024, 2048) bf16 (rows p = re, rows 512+p = im)
// ---------------------------------------------------------------------------
__global__ __launch_bounds__(256) void scan_kernel(
    const float* __restrict__ Lam, uint16_t* __restrict__ Bu) {
  const int gt = blockIdx.x * 256 + threadIdx.x;
  const int wave = gt >> 6, lane = gt & 63;
  const int b = wave >> 9, p = wave & 511;
  const float lr = Lam[p * 2 + 0], li = Lam[p * 2 + 1];
  float ar = lr, ai = li;
#pragma unroll
  for (int s = 0; s < 5; ++s) { float nr = ar * ar - ai * ai, ni = 2.f * ar * ai; ar = nr; ai = ni; }

  uint16_t* rowre = Bu + ((size_t)(b * 1024 + p)) * 2048 + lane * 32;
  uint16_t* rowim = Bu + ((size_t)(b * 1024 + 512 + p)) * 2048 + lane * 32;
  uint4 vr[4], vi[4];
#pragma unroll
  for (int q = 0; q < 4; ++q) { vr[q] = ((const uint4*)rowre)[q]; vi[q] = ((const uint4*)rowim)[q]; }

  float xr[32], xi[32];
  float sr = 0.f, si = 0.f;
#pragma unroll
  for (int q = 0; q < 4; ++q) {
    uint32_t wr[4] = {vr[q].x, vr[q].y, vr[q].z, vr[q].w};
    uint32_t wi[4] = {vi[q].x, vi[q].y, vi[q].z, vi[q].w};
#pragma unroll
    for (int d = 0; d < 4; ++d) {
      float br0 = __builtin_bit_cast(float, wr[d] << 16);
      float bi0 = __builtin_bit_cast(float, wi[d] << 16);
      float br1 = __builtin_bit_cast(float, wr[d] & 0xFFFF0000u);
      float bi1 = __builtin_bit_cast(float, wi[d] & 0xFFFF0000u);
      int j = q * 8 + d * 2;
      float nr = lr * sr - li * si + br0, ni = lr * si + li * sr + bi0;
      sr = nr; si = ni; xr[j] = sr; xi[j] = si;
      nr = lr * sr - li * si + br1; ni = lr * si + li * sr + bi1;
      sr = nr; si = ni; xr[j + 1] = sr; xi[j + 1] = si;
    }
  }
  float Ar = ar, Ai = ai, Sr = sr, Si = si;
#pragma unroll
  for (int off = 1; off < 64; off <<= 1) {
    float pAr = __shfl_up(Ar, off), pAi = __shfl_up(Ai, off);
    float pSr = __shfl_up(Sr, off), pSi = __shfl_up(Si, off);
    if (lane >= off) {
      float tSr = Ar * pSr - Ai * pSi + Sr;
      float tSi = Ar * pSi + Ai * pSr + Si;
      float tAr = Ar * pAr - Ai * pAi;
      float tAi = Ar * pAi + Ai * pAr;
      Sr = tSr; Si = tSi; Ar = tAr; Ai = tAi;
    }
  }
  float Cr = __shfl_up(Sr, 1), Ci = __shfl_up(Si, 1);
  if (lane == 0) { Cr = 0.f; Ci = 0.f; }
  float fr_ = lr * Cr - li * Ci, fi_ = lr * Ci + li * Cr;
#pragma unroll
  for (int j = 0; j < 32; ++j) {
    xr[j] += fr_; xi[j] += fi_;
    float nfr = fr_ * lr - fi_ * li, nfi = fr_ * li + fi_ * lr;
    fr_ = nfr; fi_ = nfi;
  }
#pragma unroll
  for (int q = 0; q < 4; ++q) {
    uint32_t wr[4], wi[4];
#pragma unroll
    for (int d = 0; d < 4; ++d) {
      int j = q * 8 + d * 2;
      wr[d] = (uint32_t)f2bf(xr[j]) | ((uint32_t)f2bf(xr[j + 1]) << 16);
      wi[d] = (uint32_t)f2bf(xi[j]) | ((uint32_t)f2bf(xi[j + 1]) << 16);
    }
    ((uint4*)rowre)[q] = make_uint4(wr[0], wr[1], wr[2], wr[3]);
    ((uint4*)rowim)[q] = make_uint4(wi[0], wi[1], wi[2], wi[3]);
  }
}

// ---------------------------------------------------------------------------
// GEMM1: Bu[b,m,l] = sum_h A1[m,h]*u[b,h,l]. M=1024, N=2048(xB), K=512.
// 512 threads, Tm=512 x Tn=64, 8 waves of 64m x 64n. k-chunk 128 dbuf LDS
// (B only), A frags direct from L2, XOR-swizzled B tile (2-way rd & wr).
// Barrier once per 128-k (64 MFMA/wave per barrier).
// ---------------------------------------------------------------------------
__global__ __launch_bounds__(512) void gemm1_fused(
    const uint16_t* __restrict__ A, const float* __restrict__ U,
    uint16_t* __restrict__ Bu) {
  __shared__ __align__(16) uint16_t Blds[2][64 * 136];
  const int t = threadIdx.x, lane = t & 63, w = t >> 6;
  const int m0 = blockIdx.y * 512, n0 = blockIdx.x * 64, b = blockIdx.z;
  const int fr = lane & 15, fq = lane >> 4;

  // B staging map: kr = k-pair 0..63, lc = 8-l group 0..7
  const int kr = t >> 3, lc = t & 7;
  const int wcol = (((kr >> 2) ^ lc) << 3) + (kr & 3) * 2;   // swizzled elem col
  const float* gB = U + ((size_t)b * 512 + 2 * kr) * 2048 + n0 + lc * 8;

  const uint16_t* gA = A + (size_t)(m0 + w * 64 + fr) * 512 + fq * 8;

  f32x4 acc[4][4];
#pragma unroll
  for (int i = 0; i < 4; ++i)
#pragma unroll
    for (int j = 0; j < 4; ++j) acc[i][j] = (f32x4){0.f, 0.f, 0.f, 0.f};

  int rb[4], hj[4];
#pragma unroll
  for (int j = 0; j < 4; ++j) { int n = j * 16 + fr; rb[j] = n * 136; hj[j] = n >> 3; }

  float4 p0, p1, p2, p3;
  // ---- prologue: stage period 0
  p0 = *(const float4*)(gB);
  p1 = *(const float4*)(gB + 4);
  p2 = *(const float4*)(gB + 2048);
  p3 = *(const float4*)(gB + 2052);
  {
    float r0[8] = {p0.x, p0.y, p0.z, p0.w, p1.x, p1.y, p1.z, p1.w};
    float r1[8] = {p2.x, p2.y, p2.z, p2.w, p3.x, p3.y, p3.z, p3.w};
#pragma unroll
    for (int j = 0; j < 8; ++j)
      *(uint32_t*)&Blds[0][(lc * 8 + j) * 136 + wcol] =
          (uint32_t)f2bf(r0[j]) | ((uint32_t)f2bf(r1[j]) << 16);
  }
  bf16x8 afr[2][4];
#pragma unroll
  for (int i = 0; i < 4; ++i) afr[0][i] = *(const bf16x8*)(gA + i * 8192);
  __syncthreads();

  for (int p = 0; p < 4; ++p) {
    const int cb = p & 1;
    if (p < 3) {
      const float* sp = gB + (size_t)((p + 1) * 128) * 2048;
      p0 = *(const float4*)(sp);
      p1 = *(const float4*)(sp + 4);
      p2 = *(const float4*)(sp + 2048);
      p3 = *(const float4*)(sp + 2052);
    }
#pragma unroll
    for (int s = 0; s < 4; ++s) {
      if (p < 3 || s < 3) {
        const int ks = p * 128 + (s + 1) * 32;   // s==3 rolls into next period
#pragma unroll
        for (int i = 0; i < 4; ++i)
          afr[(s + 1) & 1][i] = *(const bf16x8*)(gA + i * 8192 + ks);
      }
      bf16x8 bfr[4];
#pragma unroll
      for (int j = 0; j < 4; ++j)
        bfr[j] = *(const bf16x8*)&Blds[cb][rb[j] + ((((s * 4 + fq) ^ hj[j])) << 3)];
#pragma unroll
      for (int i = 0; i < 4; ++i)
#pragma unroll
        for (int j = 0; j < 4; ++j)
          acc[i][j] = __builtin_amdgcn_mfma_f32_16x16x32_bf16(afr[s & 1][i], bfr[j], acc[i][j], 0, 0, 0);
    }
    if (p < 3) {
      float r0[8] = {p0.x, p0.y, p0.z, p0.w, p1.x, p1.y, p1.z, p1.w};
      float r1[8] = {p2.x, p2.y, p2.z, p2.w, p3.x, p3.y, p3.z, p3.w};
#pragma unroll
      for (int j = 0; j < 8; ++j)
        *(uint32_t*)&Blds[cb ^ 1][(lc * 8 + j) * 136 + wcol] =
            (uint32_t)f2bf(r0[j]) | ((uint32_t)f2bf(r1[j]) << 16);
      __syncthreads();
    }
  }

  uint16_t* O = Bu + ((size_t)b * 1024 + m0 + w * 64) * 2048 + n0;
#pragma unroll
  for (int i = 0; i < 4; ++i)
#pragma unroll
    for (int j = 0; j < 4; ++j)
#pragma unroll
      for (int r = 0; r < 4; ++r)
        O[(size_t)(i * 16 + fq * 4 + r) * 2048 + j * 16 + fr] = f2bf(acc[i][j][r]);
}

// ---------------------------------------------------------------------------
// GEMM2: out[b,h,l] = gelu(sum_k A2[h,k]*x[b,k,l] + Dd[h]*u[b,h,l])
// M=512 (=Tm, single m-block: Bu read ONCE), N=2048(xB), K=1024. Same scheme.
// ---------------------------------------------------------------------------
__global__ __launch_bounds__(512) void gemm2_fused(
    const uint16_t* __restrict__ A, const uint16_t* __restrict__ X,
    float* __restrict__ Out, const float* __restrict__ Dd,
    const float* __restrict__ Uu) {
  __shared__ __align__(16) uint16_t Blds[2][64 * 136];
  const int t = threadIdx.x, lane = t & 63, w = t >> 6;
  const int n0 = blockIdx.x * 64, b = blockIdx.z;
  const int fr = lane & 15, fq = lane >> 4;

  const int kr = t >> 3, lc = t & 7;
  const int wcol = (((kr >> 2) ^ lc) << 3) + (kr & 3) * 2;
  const uint16_t* gB = X + ((size_t)b * 1024 + 2 * kr) * 2048 + n0 + lc * 8;

  const uint16_t* gA = A + (size_t)(w * 64 + fr) * 1024 + fq * 8;

  f32x4 acc[4][4];
#pragma unroll
  for (int i = 0; i < 4; ++i)
#pragma unroll
    for (int j = 0; j < 4; ++j) acc[i][j] = (f32x4){0.f, 0.f, 0.f, 0.f};

  int rb[4], hj[4];
#pragma unroll
  for (int j = 0; j < 4; ++j) { int n = j * 16 + fr; rb[j] = n * 136; hj[j] = n >> 3; }

  uint4 q0, q1;
  // ---- prologue: period 0
  q0 = *(const uint4*)(gB);
  q1 = *(const uint4*)(gB + 2048);
  {
    uint32_t u0[4] = {q0.x, q0.y, q0.z, q0.w};
    uint32_t u1[4] = {q1.x, q1.y, q1.z, q1.w};
#pragma unroll
    for (int d = 0; d < 4; ++d) {
      *(uint32_t*)&Blds[0][(lc * 8 + 2 * d + 0) * 136 + wcol] = (u0[d] & 0xFFFFu) | (u1[d] << 16);
      *(uint32_t*)&Blds[0][(lc * 8 + 2 * d + 1) * 136 + wcol] = (u0[d] >> 16) | (u1[d] & 0xFFFF0000u);
    }
  }
  bf16x8 afr[2][4];
#pragma unroll
  for (int i = 0; i < 4; ++i) afr[0][i] = *(const bf16x8*)(gA + i * 16384);
  __syncthreads();

  for (int p = 0; p < 8; ++p) {
    const int cb = p & 1;
    if (p < 7) {
      const uint16_t* sp = gB + (size_t)((p + 1) * 128) * 2048;
      q0 = *(const uint4*)(sp);
      q1 = *(const uint4*)(sp + 2048);
    }
#pragma unroll
    for (int s = 0; s < 4; ++s) {
      if (p < 7 || s < 3) {
        const int ks = p * 128 + (s + 1) * 32;
#pragma unroll
        for (int i = 0; i < 4; ++i)
          afr[(s + 1) & 1][i] = *(const bf16x8*)(gA + i * 16384 + ks);
      }
      bf16x8 bfr[4];
#pragma unroll
      for (int j = 0; j < 4; ++j)
        bfr[j] = *(const bf16x8*)&Blds[cb][rb[j] + ((((s * 4 + fq) ^ hj[j])) << 3)];
#pragma unroll
      for (int i = 0; i < 4; ++i)
#pragma unroll
        for (int j = 0; j < 4; ++j)
          acc[i][j] = __builtin_amdgcn_mfma_f32_16x16x32_bf16(afr[s & 1][i], bfr[j], acc[i][j], 0, 0, 0);
    }
    if (p < 7) {
      uint32_t u0[4] = {q0.x, q0.y, q0.z, q0.w};
      uint32_t u1[4] = {q1.x, q1.y, q1.z, q1.w};
#pragma unroll
      for (int d = 0; d < 4; ++d) {
        *(uint32_t*)&Blds[cb ^ 1][(lc * 8 + 2 * d + 0) * 136 + wcol] = (u0[d] & 0xFFFFu) | (u1[d] << 16);
        *(uint32_t*)&Blds[cb ^ 1][(lc * 8 + 2 * d + 1) * 136 + wcol] = (u0[d] >> 16) | (u1[d] & 0xFFFF0000u);
      }
      __syncthreads();
    }
  }

  const size_t base = ((size_t)b * 512 + w * 64) * 2048 + n0;
  float* O = Out + base;
  const float* Ub = Uu + base;
#pragma unroll
  for (int i = 0; i < 4; ++i)
#pragma unroll
    for (int r = 0; r < 4; ++r) {
      int mm = i * 16 + fq * 4 + r;
      float dv = Dd[w * 64 + mm];
#pragma unroll
      for (int j = 0; j < 4; ++j) {
        int nn = j * 16 + fr;
        float xv = acc[i][j][r] + dv * Ub[(size_t)mm * 2048 + nn];
        O[(size_t)mm * 2048 + nn] = 0.5f * xv * (1.f + erff(xv * 0.70710678118654752f));
      }
    }
}

// ---------------------------------------------------------------------------
extern "C" void kernel_launch(void* const* d_in, const int* in_sizes, int n_in,
                              void* d_out, int out_size, void* d_ws, size_t ws_size,
                              hipStream_t stream) {
  const float* u    = (const float*)d_in[0];   // (8,512,2048)
  const float* Lam  = (const float*)d_in[1];   // (512,2)
  const float* Bbar = (const float*)d_in[2];   // (512,512,2)
  const float* Cri  = (const float*)d_in[3];   // (512,512,2)
  const float* Dm   = (const float*)d_in[4];   // (512,512)
  float* out = (float*)d_out;

  char* ws = (char*)d_ws;
  uint16_t* Bu = (uint16_t*)(ws);                    // (8,1024,2048) bf16, 33.55 MB
  uint16_t* A1 = (uint16_t*)(ws + 33554432);         // (1024,512) bf16, 1 MB
  uint16_t* A2 = (uint16_t*)(ws + 34603008);         // (512,1024) bf16, 1 MB
  float*    Dd = (float*)   (ws + 35651584);         // (512) f32

  prep_mats<<<1024, 256, 0, stream>>>(Bbar, Cri, Dm, A1, A2, Dd);
  gemm1_fused<<<dim3(32, 2, BB), 512, 0, stream>>>(A1, u, Bu);
  scan_kernel<<<1024, 256, 0, stream>>>(Lam, Bu);
  gemm2_fused<<<dim3(32, 1, BB), 512, 0, stream>>>(A2, Bu, out, Dd, u);
}

// Round 6
// 195.580 us; speedup vs baseline: 1.0621x; 1.0499x over previous
//
#include <hip/hip_runtime.h>
#include <cstdint>
#include <cstddef>

// Problem dims
#define BB 8
#define HH 512
#define PP 512
#define LL 2048

typedef __attribute__((ext_vector_type(8))) __bf16 bf16x8;
typedef __attribute__((ext_vector_type(4))) float f32x4;

__device__ __forceinline__ uint16_t f2bf(float f) {
  uint32_t u = __builtin_bit_cast(uint32_t, f);
  u += 0x7FFFu + ((u >> 16) & 1u);   // RNE
  return (uint16_t)(u >> 16);
}

// ---------------------------------------------------------------------------
// prep: A1 (1024x512 bf16) = [B_re; B_im], A2 (512x1024 bf16) = [C_re, -C_im],
//       Dd (512 f32) = diag(D)
// ---------------------------------------------------------------------------
__global__ __launch_bounds__(256) void prep_mats(
    const float* __restrict__ Bbar, const float* __restrict__ Cri,
    const float* __restrict__ Dm,
    uint16_t* __restrict__ A1, uint16_t* __restrict__ A2,
    float* __restrict__ Dd) {
  int idx = blockIdx.x * 256 + threadIdx.x;   // 0 .. 512*512-1
  int p = idx >> 9, h = idx & 511;
  A1[(size_t)p * 512 + h]          = f2bf(Bbar[((size_t)p * 512 + h) * 2 + 0]);
  A1[(size_t)(512 + p) * 512 + h]  = f2bf(Bbar[((size_t)p * 512 + h) * 2 + 1]);
  int h2 = idx >> 9, p2 = idx & 511;
  A2[(size_t)h2 * 1024 + p2]        = f2bf( Cri[((size_t)h2 * 512 + p2) * 2 + 0]);
  A2[(size_t)h2 * 1024 + 512 + p2]  = f2bf(-Cri[((size_t)h2 * 512 + p2) * 2 + 1]);
  if (idx < 512) Dd[idx] = Dm[(size_t)idx * 512 + idx];
}

// ---------------------------------------------------------------------------
// scan v2: in-place on Bu (B,1024,2048) bf16. One wave per (b,p) chain.
// Global I/O fully coalesced via per-wave LDS staging with chunk swizzle
// s = c ^ ((c>>2)&7) (conflict-free at structural minimum both phases).
// ---------------------------------------------------------------------------
__global__ __launch_bounds__(256) void scan_kernel(
    const float* __restrict__ Lam, uint16_t* __restrict__ Bu) {
  __shared__ uint4 lds[4][2][256];   // [wave][re/im][16B chunk slot] = 32 KB
  const int t = threadIdx.x, lane = t & 63, wv = t >> 6;
  const int wave = blockIdx.x * 4 + wv;
  const int b = wave >> 9, p = wave & 511;
  const float lr = Lam[p * 2 + 0], li = Lam[p * 2 + 1];
  float ar = lr, ai = li;
#pragma unroll
  for (int s = 0; s < 5; ++s) { float nr = ar * ar - ai * ai, ni = 2.f * ar * ai; ar = nr; ai = ni; }

  uint4* gre = (uint4*)(Bu + ((size_t)(b * 1024 + p)) * 2048);        // 256 chunks
  uint4* gim = (uint4*)(Bu + ((size_t)(b * 1024 + 512 + p)) * 2048);

  // coalesced load: instr q covers contiguous chunks 64q..64q+63
#pragma unroll
  for (int q = 0; q < 4; ++q) {
    int c = 64 * q + lane, s = c ^ ((c >> 2) & 7);
    lds[wv][0][s] = gre[c];
    lds[wv][1][s] = gim[c];
  }
  __builtin_amdgcn_wave_barrier();
  // each lane picks up its contiguous 64 B (chunks 4*lane..4*lane+3)
  uint4 vr[4], vi[4];
#pragma unroll
  for (int d = 0; d < 4; ++d) {
    int c = 4 * lane + d, s = c ^ (lane & 7);
    vr[d] = lds[wv][0][s];
    vi[d] = lds[wv][1][s];
  }

  float xr[32], xi[32];
  float sr = 0.f, si = 0.f;
#pragma unroll
  for (int q = 0; q < 4; ++q) {
    uint32_t wr[4] = {vr[q].x, vr[q].y, vr[q].z, vr[q].w};
    uint32_t wi[4] = {vi[q].x, vi[q].y, vi[q].z, vi[q].w};
#pragma unroll
    for (int d = 0; d < 4; ++d) {
      float br0 = __builtin_bit_cast(float, wr[d] << 16);
      float bi0 = __builtin_bit_cast(float, wi[d] << 16);
      float br1 = __builtin_bit_cast(float, wr[d] & 0xFFFF0000u);
      float bi1 = __builtin_bit_cast(float, wi[d] & 0xFFFF0000u);
      int j = q * 8 + d * 2;
      float nr = lr * sr - li * si + br0, ni = lr * si + li * sr + bi0;
      sr = nr; si = ni; xr[j] = sr; xi[j] = si;
      nr = lr * sr - li * si + br1; ni = lr * si + li * sr + bi1;
      sr = nr; si = ni; xr[j + 1] = sr; xi[j + 1] = si;
    }
  }
  float Ar = ar, Ai = ai, Sr = sr, Si = si;
#pragma unroll
  for (int off = 1; off < 64; off <<= 1) {
    float pAr = __shfl_up(Ar, off), pAi = __shfl_up(Ai, off);
    float pSr = __shfl_up(Sr, off), pSi = __shfl_up(Si, off);
    if (lane >= off) {
      float tSr = Ar * pSr - Ai * pSi + Sr;
      float tSi = Ar * pSi + Ai * pSr + Si;
      float tAr = Ar * pAr - Ai * pAi;
      float tAi = Ar * pAi + Ai * pAr;
      Sr = tSr; Si = tSi; Ar = tAr; Ai = tAi;
    }
  }
  float Cr = __shfl_up(Sr, 1), Ci = __shfl_up(Si, 1);
  if (lane == 0) { Cr = 0.f; Ci = 0.f; }
  float fr_ = lr * Cr - li * Ci, fi_ = lr * Ci + li * Cr;
#pragma unroll
  for (int j = 0; j < 32; ++j) {
    xr[j] += fr_; xi[j] += fi_;
    float nfr = fr_ * lr - fi_ * li, nfi = fr_ * li + fi_ * lr;
    fr_ = nfr; fi_ = nfi;
  }
  // pack + swizzled LDS store (wave-local; DS pipe is in-order per wave)
#pragma unroll
  for (int q = 0; q < 4; ++q) {
    uint32_t wr[4], wi[4];
#pragma unroll
    for (int d = 0; d < 4; ++d) {
      int j = q * 8 + d * 2;
      wr[d] = (uint32_t)f2bf(xr[j]) | ((uint32_t)f2bf(xr[j + 1]) << 16);
      wi[d] = (uint32_t)f2bf(xi[j]) | ((uint32_t)f2bf(xi[j + 1]) << 16);
    }
    int c = 4 * lane + q, s = c ^ (lane & 7);
    lds[wv][0][s] = make_uint4(wr[0], wr[1], wr[2], wr[3]);
    lds[wv][1][s] = make_uint4(wi[0], wi[1], wi[2], wi[3]);
  }
  __builtin_amdgcn_wave_barrier();
  // coalesced store
#pragma unroll
  for (int q = 0; q < 4; ++q) {
    int c = 64 * q + lane, s = c ^ ((c >> 2) & 7);
    gre[c] = lds[wv][0][s];
    gim[c] = lds[wv][1][s];
  }
}

// ---------------------------------------------------------------------------
// GEMM1: Bu[b,m,l] = sum_h A1[m,h]*u[b,h,l]. M=1024, N=2048(xB), K=512.
// 512 threads, Tm=512 x Tn=64, 8 waves of 64m x 64n. (unchanged from R5)
// ---------------------------------------------------------------------------
__global__ __launch_bounds__(512) void gemm1_fused(
    const uint16_t* __restrict__ A, const float* __restrict__ U,
    uint16_t* __restrict__ Bu) {
  __shared__ __align__(16) uint16_t Blds[2][64 * 136];
  const int t = threadIdx.x, lane = t & 63, w = t >> 6;
  const int m0 = blockIdx.y * 512, n0 = blockIdx.x * 64, b = blockIdx.z;
  const int fr = lane & 15, fq = lane >> 4;

  const int kr = t >> 3, lc = t & 7;
  const int wcol = (((kr >> 2) ^ lc) << 3) + (kr & 3) * 2;
  const float* gB = U + ((size_t)b * 512 + 2 * kr) * 2048 + n0 + lc * 8;

  const uint16_t* gA = A + (size_t)(m0 + w * 64 + fr) * 512 + fq * 8;

  f32x4 acc[4][4];
#pragma unroll
  for (int i = 0; i < 4; ++i)
#pragma unroll
    for (int j = 0; j < 4; ++j) acc[i][j] = (f32x4){0.f, 0.f, 0.f, 0.f};

  int rb[4], hj[4];
#pragma unroll
  for (int j = 0; j < 4; ++j) { int n = j * 16 + fr; rb[j] = n * 136; hj[j] = n >> 3; }

  float4 p0, p1, p2, p3;
  p0 = *(const float4*)(gB);
  p1 = *(const float4*)(gB + 4);
  p2 = *(const float4*)(gB + 2048);
  p3 = *(const float4*)(gB + 2052);
  {
    float r0[8] = {p0.x, p0.y, p0.z, p0.w, p1.x, p1.y, p1.z, p1.w};
    float r1[8] = {p2.x, p2.y, p2.z, p2.w, p3.x, p3.y, p3.z, p3.w};
#pragma unroll
    for (int j = 0; j < 8; ++j)
      *(uint32_t*)&Blds[0][(lc * 8 + j) * 136 + wcol] =
          (uint32_t)f2bf(r0[j]) | ((uint32_t)f2bf(r1[j]) << 16);
  }
  bf16x8 afr[2][4];
#pragma unroll
  for (int i = 0; i < 4; ++i) afr[0][i] = *(const bf16x8*)(gA + i * 8192);
  __syncthreads();

  for (int p = 0; p < 4; ++p) {
    const int cb = p & 1;
    if (p < 3) {
      const float* sp = gB + (size_t)((p + 1) * 128) * 2048;
      p0 = *(const float4*)(sp);
      p1 = *(const float4*)(sp + 4);
      p2 = *(const float4*)(sp + 2048);
      p3 = *(const float4*)(sp + 2052);
    }
#pragma unroll
    for (int s = 0; s < 4; ++s) {
      if (p < 3 || s < 3) {
        const int ks = p * 128 + (s + 1) * 32;
#pragma unroll
        for (int i = 0; i < 4; ++i)
          afr[(s + 1) & 1][i] = *(const bf16x8*)(gA + i * 8192 + ks);
      }
      bf16x8 bfr[4];
#pragma unroll
      for (int j = 0; j < 4; ++j)
        bfr[j] = *(const bf16x8*)&Blds[cb][rb[j] + ((((s * 4 + fq) ^ hj[j])) << 3)];
#pragma unroll
      for (int i = 0; i < 4; ++i)
#pragma unroll
        for (int j = 0; j < 4; ++j)
          acc[i][j] = __builtin_amdgcn_mfma_f32_16x16x32_bf16(afr[s & 1][i], bfr[j], acc[i][j], 0, 0, 0);
    }
    if (p < 3) {
      float r0[8] = {p0.x, p0.y, p0.z, p0.w, p1.x, p1.y, p1.z, p1.w};
      float r1[8] = {p2.x, p2.y, p2.z, p2.w, p3.x, p3.y, p3.z, p3.w};
#pragma unroll
      for (int j = 0; j < 8; ++j)
        *(uint32_t*)&Blds[cb ^ 1][(lc * 8 + j) * 136 + wcol] =
            (uint32_t)f2bf(r0[j]) | ((uint32_t)f2bf(r1[j]) << 16);
      __syncthreads();
    }
  }

  uint16_t* O = Bu + ((size_t)b * 1024 + m0 + w * 64) * 2048 + n0;
#pragma unroll
  for (int i = 0; i < 4; ++i)
#pragma unroll
    for (int j = 0; j < 4; ++j)
#pragma unroll
      for (int r = 0; r < 4; ++r)
        O[(size_t)(i * 16 + fq * 4 + r) * 2048 + j * 16 + fr] = f2bf(acc[i][j][r]);
}

// ---------------------------------------------------------------------------
// GEMM2: out[b,h,l] = gelu(sum_k A2[h,k]*x[b,k,l] + Dd[h]*u[b,h,l])
// M=512, N=2048(xB), K=1024. 256 threads, Tm=256 x Tn=64, 4 waves of 64x64.
// Grid 32x2x8 = 512 blocks (2/CU) -> two independent barrier cliques per CU.
// ---------------------------------------------------------------------------
__global__ __launch_bounds__(256) void gemm2_fused(
    const uint16_t* __restrict__ A, const uint16_t* __restrict__ X,
    float* __restrict__ Out, const float* __restrict__ Dd,
    const float* __restrict__ Uu) {
  __shared__ __align__(16) uint16_t Blds[2][64 * 136];
  const int t = threadIdx.x, lane = t & 63, w = t >> 6;           // w = 0..3
  const int m0 = blockIdx.y * 256, n0 = blockIdx.x * 64, b = blockIdx.z;
  const int fr = lane & 15, fq = lane >> 4;

  // B staging: 256 threads stage 128k x 64l per period; each thread covers
  // k-pairs kr and kr+32 (kr = t>>3, 0..31), lc = t&7 (8-l group).
  const int kr = t >> 3, lc = t & 7;
  const int wcolA = (((kr >> 2) ^ lc) << 3) + (kr & 3) * 2;
  const int wcolB = ((((kr >> 2) + 8) ^ lc) << 3) + (kr & 3) * 2;
  const uint16_t* gBa = X + ((size_t)b * 1024 + 2 * kr) * 2048 + n0 + lc * 8;
  const uint16_t* gBb = gBa + (size_t)64 * 2048;                  // k-pairs +32

  const uint16_t* gA = A + (size_t)(m0 + w * 64 + fr) * 1024 + fq * 8;

  f32x4 acc[4][4];
#pragma unroll
  for (int i = 0; i < 4; ++i)
#pragma unroll
    for (int j = 0; j < 4; ++j) acc[i][j] = (f32x4){0.f, 0.f, 0.f, 0.f};

  int rb[4], hj[4];
#pragma unroll
  for (int j = 0; j < 4; ++j) { int n = j * 16 + fr; rb[j] = n * 136; hj[j] = n >> 3; }

  uint4 qa0, qa1, qb0, qb1;
  // ---- prologue: period 0
  qa0 = *(const uint4*)(gBa);
  qa1 = *(const uint4*)(gBa + 2048);
  qb0 = *(const uint4*)(gBb);
  qb1 = *(const uint4*)(gBb + 2048);
  {
    uint32_t u0[4] = {qa0.x, qa0.y, qa0.z, qa0.w};
    uint32_t u1[4] = {qa1.x, qa1.y, qa1.z, qa1.w};
    uint32_t v0[4] = {qb0.x, qb0.y, qb0.z, qb0.w};
    uint32_t v1[4] = {qb1.x, qb1.y, qb1.z, qb1.w};
#pragma unroll
    for (int d = 0; d < 4; ++d) {
      *(uint32_t*)&Blds[0][(lc * 8 + 2 * d + 0) * 136 + wcolA] = (u0[d] & 0xFFFFu) | (u1[d] << 16);
      *(uint32_t*)&Blds[0][(lc * 8 + 2 * d + 1) * 136 + wcolA] = (u0[d] >> 16) | (u1[d] & 0xFFFF0000u);
      *(uint32_t*)&Blds[0][(lc * 8 + 2 * d + 0) * 136 + wcolB] = (v0[d] & 0xFFFFu) | (v1[d] << 16);
      *(uint32_t*)&Blds[0][(lc * 8 + 2 * d + 1) * 136 + wcolB] = (v0[d] >> 16) | (v1[d] & 0xFFFF0000u);
    }
  }
  bf16x8 afr[2][4];
#pragma unroll
  for (int i = 0; i < 4; ++i) afr[0][i] = *(const bf16x8*)(gA + i * 16384);
  __syncthreads();

  for (int p = 0; p < 8; ++p) {
    const int cb = p & 1;
    if (p < 7) {
      const uint16_t* spa = gBa + (size_t)((p + 1) * 128) * 2048;
      qa0 = *(const uint4*)(spa);
      qa1 = *(const uint4*)(spa + 2048);
      qb0 = *(const uint4*)(spa + (size_t)64 * 2048);
      qb1 = *(const uint4*)(spa + (size_t)65 * 2048);
    }
#pragma unroll
    for (int s = 0; s < 4; ++s) {
      if (p < 7 || s < 3) {
        const int ks = p * 128 + (s + 1) * 32;
#pragma unroll
        for (int i = 0; i < 4; ++i)
          afr[(s + 1) & 1][i] = *(const bf16x8*)(gA + i * 16384 + ks);
      }
      bf16x8 bfr[4];
#pragma unroll
      for (int j = 0; j < 4; ++j)
        bfr[j] = *(const bf16x8*)&Blds[cb][rb[j] + ((((s * 4 + fq) ^ hj[j])) << 3)];
#pragma unroll
      for (int i = 0; i < 4; ++i)
#pragma unroll
        for (int j = 0; j < 4; ++j)
          acc[i][j] = __builtin_amdgcn_mfma_f32_16x16x32_bf16(afr[s & 1][i], bfr[j], acc[i][j], 0, 0, 0);
    }
    if (p < 7) {
      uint32_t u0[4] = {qa0.x, qa0.y, qa0.z, qa0.w};
      uint32_t u1[4] = {qa1.x, qa1.y, qa1.z, qa1.w};
      uint32_t v0[4] = {qb0.x, qb0.y, qb0.z, qb0.w};
      uint32_t v1[4] = {qb1.x, qb1.y, qb1.z, qb1.w};
#pragma unroll
      for (int d = 0; d < 4; ++d) {
        *(uint32_t*)&Blds[cb ^ 1][(lc * 8 + 2 * d + 0) * 136 + wcolA] = (u0[d] & 0xFFFFu) | (u1[d] << 16);
        *(uint32_t*)&Blds[cb ^ 1][(lc * 8 + 2 * d + 1) * 136 + wcolA] = (u0[d] >> 16) | (u1[d] & 0xFFFF0000u);
        *(uint32_t*)&Blds[cb ^ 1][(lc * 8 + 2 * d + 0) * 136 + wcolB] = (v0[d] & 0xFFFFu) | (v1[d] << 16);
        *(uint32_t*)&Blds[cb ^ 1][(lc * 8 + 2 * d + 1) * 136 + wcolB] = (v0[d] >> 16) | (v1[d] & 0xFFFF0000u);
      }
      __syncthreads();
    }
  }

  const size_t base = ((size_t)b * 512 + m0 + w * 64) * 2048 + n0;
  float* O = Out + base;
  const float* Ub = Uu + base;
#pragma unroll
  for (int i = 0; i < 4; ++i)
#pragma unroll
    for (int r = 0; r < 4; ++r) {
      int mm = i * 16 + fq * 4 + r;
      float dv = Dd[m0 + w * 64 + mm];
#pragma unroll
      for (int j = 0; j < 4; ++j) {
        int nn = j * 16 + fr;
        float xv = acc[i][j][r] + dv * Ub[(size_t)mm * 2048 + nn];
        O[(size_t)mm * 2048 + nn] = 0.5f * xv * (1.f + erff(xv * 0.70710678118654752f));
      }
    }
}

// ---------------------------------------------------------------------------
extern "C" void kernel_launch(void* const* d_in, const int* in_sizes, int n_in,
                              void* d_out, int out_size, void* d_ws, size_t ws_size,
                              hipStream_t stream) {
  const float* u    = (const float*)d_in[0];   // (8,512,2048)
  const float* Lam  = (const float*)d_in[1];   // (512,2)
  const float* Bbar = (const float*)d_in[2];   // (512,512,2)
  const float* Cri  = (const float*)d_in[3];   // (512,512,2)
  const float* Dm   = (const float*)d_in[4];   // (512,512)
  float* out = (float*)d_out;

  char* ws = (char*)d_ws;
  uint16_t* Bu = (uint16_t*)(ws);                    // (8,1024,2048) bf16, 33.55 MB
  uint16_t* A1 = (uint16_t*)(ws + 33554432);         // (1024,512) bf16, 1 MB
  uint16_t* A2 = (uint16_t*)(ws + 34603008);         // (512,1024) bf16, 1 MB
  float*    Dd = (float*)   (ws + 35651584);         // (512) f32

  prep_mats<<<1024, 256, 0, stream>>>(Bbar, Cri, Dm, A1, A2, Dd);
  gemm1_fused<<<dim3(32, 2, BB), 512, 0, stream>>>(A1, u, Bu);
  scan_kernel<<<1024, 256, 0, stream>>>(Lam, Bu);
  gemm2_fused<<<dim3(32, 2, BB), 256, 0, stream>>>(A2, Bu, out, Dd, u);
}

// Round 7
// 193.736 us; speedup vs baseline: 1.0722x; 1.0095x over previous
//
#include <hip/hip_runtime.h>
#include <cstdint>
#include <cstddef>

// Problem dims
#define BB 8
#define HH 512
#define PP 512
#define LL 2048

typedef __attribute__((ext_vector_type(8))) __bf16 bf16x8;
typedef __attribute__((ext_vector_type(4))) float f32x4;

__device__ __forceinline__ uint16_t f2bf(float f) {
  uint32_t u = __builtin_bit_cast(uint32_t, f);
  u += 0x7FFFu + ((u >> 16) & 1u);   // RNE
  return (uint16_t)(u >> 16);
}

__device__ __forceinline__ void async_copy16(const void* gptr, void* ldsptr) {
  __builtin_amdgcn_global_load_lds(
      (const __attribute__((address_space(1))) unsigned int*)gptr,
      (__attribute__((address_space(3))) unsigned int*)ldsptr,
      16, 0, 0);
}

__device__ __forceinline__ float gelu_f(float x) {
  float x3 = x * x * x;
  float y = 0.7978845608028654f * (x + 0.044715f * x3);
  float e = __expf(-2.0f * fabsf(y));
  float th = (1.0f - e) / (1.0f + e);        // tanh(|y|)
  th = copysignf(th, y);
  return 0.5f * x * (1.0f + th);
}

// ---------------------------------------------------------------------------
// prep: A1 (1024x512 bf16) = [B_re; B_im], A2 (512x1024 bf16) = [C_re, -C_im],
//       Dd (512 f32) = diag(D)
// ---------------------------------------------------------------------------
__global__ __launch_bounds__(256) void prep_mats(
    const float* __restrict__ Bbar, const float* __restrict__ Cri,
    const float* __restrict__ Dm,
    uint16_t* __restrict__ A1, uint16_t* __restrict__ A2,
    float* __restrict__ Dd) {
  int idx = blockIdx.x * 256 + threadIdx.x;   // 0 .. 512*512-1
  int p = idx >> 9, h = idx & 511;
  A1[(size_t)p * 512 + h]          = f2bf(Bbar[((size_t)p * 512 + h) * 2 + 0]);
  A1[(size_t)(512 + p) * 512 + h]  = f2bf(Bbar[((size_t)p * 512 + h) * 2 + 1]);
  int h2 = idx >> 9, p2 = idx & 511;
  A2[(size_t)h2 * 1024 + p2]        = f2bf( Cri[((size_t)h2 * 512 + p2) * 2 + 0]);
  A2[(size_t)h2 * 1024 + 512 + p2]  = f2bf(-Cri[((size_t)h2 * 512 + p2) * 2 + 1]);
  if (idx < 512) Dd[idx] = Dm[(size_t)idx * 512 + idx];
}

// ---------------------------------------------------------------------------
// scan v2 (proven R6): in-place on Bu (B,1024,2048) bf16. One wave per chain;
// coalesced global I/O via swizzled per-wave LDS staging.
// ---------------------------------------------------------------------------
__global__ __launch_bounds__(256) void scan_kernel(
    const float* __restrict__ Lam, uint16_t* __restrict__ Bu) {
  __shared__ uint4 lds[4][2][256];
  const int t = threadIdx.x, lane = t & 63, wv = t >> 6;
  const int wave = blockIdx.x * 4 + wv;
  const int b = wave >> 9, p = wave & 511;
  const float lr = Lam[p * 2 + 0], li = Lam[p * 2 + 1];
  float ar = lr, ai = li;
#pragma unroll
  for (int s = 0; s < 5; ++s) { float nr = ar * ar - ai * ai, ni = 2.f * ar * ai; ar = nr; ai = ni; }

  uint4* gre = (uint4*)(Bu + ((size_t)(b * 1024 + p)) * 2048);
  uint4* gim = (uint4*)(Bu + ((size_t)(b * 1024 + 512 + p)) * 2048);

#pragma unroll
  for (int q = 0; q < 4; ++q) {
    int c = 64 * q + lane, s = c ^ ((c >> 2) & 7);
    lds[wv][0][s] = gre[c];
    lds[wv][1][s] = gim[c];
  }
  __builtin_amdgcn_wave_barrier();
  uint4 vr[4], vi[4];
#pragma unroll
  for (int d = 0; d < 4; ++d) {
    int c = 4 * lane + d, s = c ^ (lane & 7);
    vr[d] = lds[wv][0][s];
    vi[d] = lds[wv][1][s];
  }

  float xr[32], xi[32];
  float sr = 0.f, si = 0.f;
#pragma unroll
  for (int q = 0; q < 4; ++q) {
    uint32_t wr[4] = {vr[q].x, vr[q].y, vr[q].z, vr[q].w};
    uint32_t wi[4] = {vi[q].x, vi[q].y, vi[q].z, vi[q].w};
#pragma unroll
    for (int d = 0; d < 4; ++d) {
      float br0 = __builtin_bit_cast(float, wr[d] << 16);
      float bi0 = __builtin_bit_cast(float, wi[d] << 16);
      float br1 = __builtin_bit_cast(float, wr[d] & 0xFFFF0000u);
      float bi1 = __builtin_bit_cast(float, wi[d] & 0xFFFF0000u);
      int j = q * 8 + d * 2;
      float nr = lr * sr - li * si + br0, ni = lr * si + li * sr + bi0;
      sr = nr; si = ni; xr[j] = sr; xi[j] = si;
      nr = lr * sr - li * si + br1; ni = lr * si + li * sr + bi1;
      sr = nr; si = ni; xr[j + 1] = sr; xi[j + 1] = si;
    }
  }
  float Ar = ar, Ai = ai, Sr = sr, Si = si;
#pragma unroll
  for (int off = 1; off < 64; off <<= 1) {
    float pAr = __shfl_up(Ar, off), pAi = __shfl_up(Ai, off);
    float pSr = __shfl_up(Sr, off), pSi = __shfl_up(Si, off);
    if (lane >= off) {
      float tSr = Ar * pSr - Ai * pSi + Sr;
      float tSi = Ar * pSi + Ai * pSr + Si;
      float tAr = Ar * pAr - Ai * pAi;
      float tAi = Ar * pAi + Ai * pAr;
      Sr = tSr; Si = tSi; Ar = tAr; Ai = tAi;
    }
  }
  float Cr = __shfl_up(Sr, 1), Ci = __shfl_up(Si, 1);
  if (lane == 0) { Cr = 0.f; Ci = 0.f; }
  float fr_ = lr * Cr - li * Ci, fi_ = lr * Ci + li * Cr;
#pragma unroll
  for (int j = 0; j < 32; ++j) {
    xr[j] += fr_; xi[j] += fi_;
    float nfr = fr_ * lr - fi_ * li, nfi = fr_ * li + fi_ * lr;
    fr_ = nfr; fi_ = nfi;
  }
#pragma unroll
  for (int q = 0; q < 4; ++q) {
    uint32_t wr[4], wi[4];
#pragma unroll
    for (int d = 0; d < 4; ++d) {
      int j = q * 8 + d * 2;
      wr[d] = (uint32_t)f2bf(xr[j]) | ((uint32_t)f2bf(xr[j + 1]) << 16);
      wi[d] = (uint32_t)f2bf(xi[j]) | ((uint32_t)f2bf(xi[j + 1]) << 16);
    }
    int c = 4 * lane + q, s = c ^ (lane & 7);
    lds[wv][0][s] = make_uint4(wr[0], wr[1], wr[2], wr[3]);
    lds[wv][1][s] = make_uint4(wi[0], wi[1], wi[2], wi[3]);
  }
  __builtin_amdgcn_wave_barrier();
#pragma unroll
  for (int q = 0; q < 4; ++q) {
    int c = 64 * q + lane, s = c ^ ((c >> 2) & 7);
    gre[c] = lds[wv][0][s];
    gim[c] = lds[wv][1][s];
  }
}

// ---------------------------------------------------------------------------
// LDS->LDS transpose steps (raw [k][l] DMA layout -> trans [l][k] swizzled).
// Raw storage is source-octet-swizzled: stored[k][c] = global octet c ^ (k&7)
// (bf16) / quad c ^ (k&15) (f32), so reads below are bank-uniform.
// trans element (l,k) at col ((k>>3)^(l>>3))*8 + (k&7)  [R6-proven formulas]
// ---------------------------------------------------------------------------
__device__ __forceinline__ void transpose_step_bf16(
    const uint16_t* __restrict__ rawp, uint16_t* __restrict__ trp,
    int kr0, int lg) {
  const int k0 = 2 * kr0, k1 = 2 * kr0 + 1;
  uint4 r0 = *(const uint4*)&rawp[k0 * 64 + ((lg ^ (k0 & 7)) << 3)];
  uint4 r1 = *(const uint4*)&rawp[k1 * 64 + ((lg ^ (k1 & 7)) << 3)];
  uint32_t u0[4] = {r0.x, r0.y, r0.z, r0.w};
  uint32_t u1[4] = {r1.x, r1.y, r1.z, r1.w};
  uint16_t* base = trp + lg * 8 * 136 + (((kr0 >> 2) ^ lg) * 8 + (kr0 & 3) * 2);
#pragma unroll
  for (int d = 0; d < 4; ++d) {
    *(uint32_t*)&base[(2 * d) * 136]     = (u0[d] & 0xFFFFu) | (u1[d] << 16);
    *(uint32_t*)&base[(2 * d + 1) * 136] = (u0[d] >> 16) | (u1[d] & 0xFFFF0000u);
  }
}

__device__ __forceinline__ void transpose_step_f32(
    const float* __restrict__ rawp, uint16_t* __restrict__ trp,
    int kr0, int lg) {
  const int k0 = 2 * kr0, k1 = 2 * kr0 + 1;
  float4 a0 = *(const float4*)&rawp[k0 * 64 + ((((lg * 2)     ^ (k0 & 15))) << 2)];
  float4 a1 = *(const float4*)&rawp[k0 * 64 + ((((lg * 2 + 1) ^ (k0 & 15))) << 2)];
  float4 b0 = *(const float4*)&rawp[k1 * 64 + ((((lg * 2)     ^ (k1 & 15))) << 2)];
  float4 b1 = *(const float4*)&rawp[k1 * 64 + ((((lg * 2 + 1) ^ (k1 & 15))) << 2)];
  float r0[8] = {a0.x, a0.y, a0.z, a0.w, a1.x, a1.y, a1.z, a1.w};
  float r1[8] = {b0.x, b0.y, b0.z, b0.w, b1.x, b1.y, b1.z, b1.w};
  uint16_t* base = trp + lg * 8 * 72 + (((kr0 >> 2) ^ lg) * 8 + (kr0 & 3) * 2);
#pragma unroll
  for (int j = 0; j < 8; ++j)
    *(uint32_t*)&base[j * 72] = (uint32_t)f2bf(r0[j]) | ((uint32_t)f2bf(r1[j]) << 16);
}

// ---------------------------------------------------------------------------
// GEMM1: Bu[b,m,l] = sum_h A1[m,h]*u[b,h,l]. M=1024, N=2048(xB), K=512.
// 256 thr, Tm=256 (4 waves x 64m), Tn=64, period=64k, 8 periods.
// 3-stage pipeline: DMA raw (f32, +2 periods) / transpose (+1) / MFMA.
// ---------------------------------------------------------------------------
__global__ __launch_bounds__(256) void gemm1_fused(
    const uint16_t* __restrict__ A, const float* __restrict__ U,
    uint16_t* __restrict__ Bu) {
  __shared__ __align__(16) float    rawf[2][64 * 64];    // 16 KB x2
  __shared__ __align__(16) uint16_t trans[2][64 * 72];   //  9 KB x2
  const int t = threadIdx.x, lane = t & 63, w = t >> 6;
  const int m0 = blockIdx.y * 256, n0 = blockIdx.x * 64, b = blockIdx.z;
  const int fr = lane & 15, fq = lane >> 4;
  const int kr = t >> 3, lg = t & 7;

  const float* gsrc = U + ((size_t)b * 512 + (t >> 4)) * 2048 + n0
                        + ((((t & 15) ^ ((t >> 4) & 15))) << 2);
  const uint16_t* gA[4];
#pragma unroll
  for (int i = 0; i < 4; ++i)
    gA[i] = A + (size_t)(m0 + w * 64 + i * 16 + fr) * 512 + fq * 8;
  int rb[4], hj[4];
#pragma unroll
  for (int j = 0; j < 4; ++j) { int n = j * 16 + fr; rb[j] = n * 72; hj[j] = n >> 3; }

  f32x4 acc[4][4];
#pragma unroll
  for (int i = 0; i < 4; ++i)
#pragma unroll
    for (int j = 0; j < 4; ++j) acc[i][j] = (f32x4){0.f, 0.f, 0.f, 0.f};

  // ---- prologue
#pragma unroll
  for (int c = 0; c < 4; ++c)
    async_copy16(gsrc + (size_t)(c * 16) * 2048, &rawf[0][t * 4 + c * 1024]);
  __syncthreads();                      // raw[0] = period 0
  transpose_step_f32(rawf[0], trans[0], kr, lg);
#pragma unroll
  for (int c = 0; c < 4; ++c)
    async_copy16(gsrc + (size_t)(64 + c * 16) * 2048, &rawf[1][t * 4 + c * 1024]);
  bf16x8 afr[2][4];
#pragma unroll
  for (int i = 0; i < 4; ++i) afr[0][i] = *(const bf16x8*)(gA[i]);
  __syncthreads();                      // trans[0] ready, raw[1] = period 1

  for (int p = 0; p < 8; ++p) {
    const int cur = p & 1, nxt = cur ^ 1;
    if (p + 2 < 8) {
      const size_t koff = (size_t)((p + 2) * 64) * 2048;
#pragma unroll
      for (int c = 0; c < 4; ++c)
        async_copy16(gsrc + koff + (size_t)(c * 16) * 2048, &rawf[cur][t * 4 + c * 1024]);
    }
    if (p + 1 < 8)
      transpose_step_f32(rawf[nxt], trans[nxt], kr, lg);
#pragma unroll
    for (int s = 0; s < 2; ++s) {
      const int kn = p * 64 + (s + 1) * 32;
      if (kn < 512) {
#pragma unroll
        for (int i = 0; i < 4; ++i)
          afr[(s + 1) & 1][i] = *(const bf16x8*)(gA[i] + kn);
      }
      bf16x8 bfr[4];
#pragma unroll
      for (int j = 0; j < 4; ++j)
        bfr[j] = *(const bf16x8*)&trans[cur][rb[j] + (((s * 4 + fq) ^ hj[j]) << 3)];
#pragma unroll
      for (int i = 0; i < 4; ++i)
#pragma unroll
        for (int j = 0; j < 4; ++j)
          acc[i][j] = __builtin_amdgcn_mfma_f32_16x16x32_bf16(afr[s & 1][i], bfr[j], acc[i][j], 0, 0, 0);
    }
    if (p < 7) __syncthreads();
  }

  uint16_t* O = Bu + ((size_t)b * 1024 + m0 + w * 64) * 2048 + n0;
#pragma unroll
  for (int i = 0; i < 4; ++i)
#pragma unroll
    for (int j = 0; j < 4; ++j)
#pragma unroll
      for (int r = 0; r < 4; ++r)
        O[(size_t)(i * 16 + fq * 4 + r) * 2048 + j * 16 + fr] = f2bf(acc[i][j][r]);
}

// ---------------------------------------------------------------------------
// GEMM2: out[b,h,l] = gelu(sum_k A2[h,k]*x[b,k,l] + Dd[h]*u[b,h,l])
// M=512, N=2048(xB), K=1024. 256 thr, Tm=256, Tn=64, period=128k, 8 periods.
// Same 3-stage pipeline, bf16 raw.
// ---------------------------------------------------------------------------
__global__ __launch_bounds__(256) void gemm2_fused(
    const uint16_t* __restrict__ A, const uint16_t* __restrict__ X,
    float* __restrict__ Out, const float* __restrict__ Dd,
    const float* __restrict__ Uu) {
  __shared__ __align__(16) uint16_t rawb[2][128 * 64];   // 16 KB x2
  __shared__ __align__(16) uint16_t trans[2][64 * 136];  // 17 KB x2
  const int t = threadIdx.x, lane = t & 63, w = t >> 6;
  const int m0 = blockIdx.y * 256, n0 = blockIdx.x * 64, b = blockIdx.z;
  const int fr = lane & 15, fq = lane >> 4;
  const int kr = t >> 3, lg = t & 7;

  const uint16_t* gsrc = X + ((size_t)b * 1024 + (t >> 3)) * 2048 + n0
                           + ((((t & 7) ^ ((t >> 3) & 7))) << 3);
  const uint16_t* gA[4];
#pragma unroll
  for (int i = 0; i < 4; ++i)
    gA[i] = A + (size_t)(m0 + w * 64 + i * 16 + fr) * 1024 + fq * 8;
  int rb[4], hj[4];
#pragma unroll
  for (int j = 0; j < 4; ++j) { int n = j * 16 + fr; rb[j] = n * 136; hj[j] = n >> 3; }

  f32x4 acc[4][4];
#pragma unroll
  for (int i = 0; i < 4; ++i)
#pragma unroll
    for (int j = 0; j < 4; ++j) acc[i][j] = (f32x4){0.f, 0.f, 0.f, 0.f};

  // ---- prologue
#pragma unroll
  for (int c = 0; c < 4; ++c)
    async_copy16(gsrc + (size_t)(c * 32) * 2048, &rawb[0][t * 8 + c * 2048]);
  __syncthreads();                      // raw[0] = period 0
  transpose_step_bf16(rawb[0], trans[0], kr, lg);
  transpose_step_bf16(rawb[0], trans[0], kr + 32, lg);
#pragma unroll
  for (int c = 0; c < 4; ++c)
    async_copy16(gsrc + (size_t)(128 + c * 32) * 2048, &rawb[1][t * 8 + c * 2048]);
  bf16x8 afr[2][4];
#pragma unroll
  for (int i = 0; i < 4; ++i) afr[0][i] = *(const bf16x8*)(gA[i]);
  __syncthreads();                      // trans[0] ready, raw[1] = period 1

  for (int p = 0; p < 8; ++p) {
    const int cur = p & 1, nxt = cur ^ 1;
    if (p + 2 < 8) {
      const size_t koff = (size_t)((p + 2) * 128) * 2048;
#pragma unroll
      for (int c = 0; c < 4; ++c)
        async_copy16(gsrc + koff + (size_t)(c * 32) * 2048, &rawb[cur][t * 8 + c * 2048]);
    }
    if (p + 1 < 8) {
      transpose_step_bf16(rawb[nxt], trans[nxt], kr, lg);
      transpose_step_bf16(rawb[nxt], trans[nxt], kr + 32, lg);
    }
#pragma unroll
    for (int s = 0; s < 4; ++s) {
      const int kn = p * 128 + (s + 1) * 32;
      if (kn < 1024) {
#pragma unroll
        for (int i = 0; i < 4; ++i)
          afr[(s + 1) & 1][i] = *(const bf16x8*)(gA[i] + kn);
      }
      bf16x8 bfr[4];
#pragma unroll
      for (int j = 0; j < 4; ++j)
        bfr[j] = *(const bf16x8*)&trans[cur][rb[j] + (((s * 4 + fq) ^ hj[j]) << 3)];
#pragma unroll
      for (int i = 0; i < 4; ++i)
#pragma unroll
        for (int j = 0; j < 4; ++j)
          acc[i][j] = __builtin_amdgcn_mfma_f32_16x16x32_bf16(afr[s & 1][i], bfr[j], acc[i][j], 0, 0, 0);
    }
    if (p < 7) __syncthreads();
  }

  const size_t base = ((size_t)b * 512 + m0 + w * 64) * 2048 + n0;
  float* O = Out + base;
  const float* Ub = Uu + base;
#pragma unroll
  for (int i = 0; i < 4; ++i)
#pragma unroll
    for (int r = 0; r < 4; ++r) {
      int mm = i * 16 + fq * 4 + r;
      float dv = Dd[m0 + w * 64 + mm];
#pragma unroll
      for (int j = 0; j < 4; ++j) {
        int nn = j * 16 + fr;
        float xv = acc[i][j][r] + dv * Ub[(size_t)mm * 2048 + nn];
        O[(size_t)mm * 2048 + nn] = gelu_f(xv);
      }
    }
}

// ---------------------------------------------------------------------------
extern "C" void kernel_launch(void* const* d_in, const int* in_sizes, int n_in,
                              void* d_out, int out_size, void* d_ws, size_t ws_size,
                              hipStream_t stream) {
  const float* u    = (const float*)d_in[0];   // (8,512,2048)
  const float* Lam  = (const float*)d_in[1];   // (512,2)
  const float* Bbar = (const float*)d_in[2];   // (512,512,2)
  const float* Cri  = (const float*)d_in[3];   // (512,512,2)
  const float* Dm   = (const float*)d_in[4];   // (512,512)
  float* out = (float*)d_out;

  char* ws = (char*)d_ws;
  uint16_t* Bu = (uint16_t*)(ws);                    // (8,1024,2048) bf16, 33.55 MB
  uint16_t* A1 = (uint16_t*)(ws + 33554432);         // (1024,512) bf16, 1 MB
  uint16_t* A2 = (uint16_t*)(ws + 34603008);         // (512,1024) bf16, 1 MB
  float*    Dd = (float*)   (ws + 35651584);         // (512) f32

  prep_mats<<<1024, 256, 0, stream>>>(Bbar, Cri, Dm, A1, A2, Dd);
  gemm1_fused<<<dim3(32, 4, BB), 256, 0, stream>>>(A1, u, Bu);
  scan_kernel<<<1024, 256, 0, stream>>>(Lam, Bu);
  gemm2_fused<<<dim3(32, 2, BB), 256, 0, stream>>>(A2, Bu, out, Dd, u);
}